// Round 8
// baseline (223.209 us; speedup 1.0000x reference)
//
#include <hip/hip_runtime.h>
#include <math.h>

// ---------------------------------------------------------------------------
// TimeAttender: S=2048, B=32, D=512, K=147
// out = concat(applied [B*D], norm_w [B*S])
//
// Math notes:
//  * prev_probs normalizer and softmax Z cancel in
//      norm_w = adj * exp(w) / sum_s(adj * exp(w))
//  * w is a cosine similarity in [-1,1] -> exp(w) in [0.37, 2.72]:
//    no max-subtraction needed; apply pass is single-pass over e.
//  * SESSION LEDGER (R0..R7) — read before "optimizing":
//    - Fixed harness cost ~157 us (512 MiB poison fills + resets) dominates.
//    - R2: last-block fusion w/ __threadfence = L2-writeback storm (+55).
//    - R4: contiguous-vs-strided e walk: NEUTRAL. Pattern not the limiter.
//    - R5: register-resident 16-row pipeline: VGPR spills (+56).
//    - R6: global_load_lds ring + counted vmcnt: +29 (compiler drains
//      vmcnt before aliasing ds_reads; guide §5 m131-m141 trap).
//    - R7: NON-TEMPORAL loads on the e stream: -9.1 us (210.9, best).
//      Mechanism confirmed: read-once stream was evicting the live set
//      from L2 / forcing victim writebacks. First main-side win.
//    - This round: nt extended to W/partial/u drains; NCHUNK 128->256
//      (CH=8, 8 waves/SIMD) — occupancy was neutral PRE-nt (R3) but the
//      bottleneck has moved; retest under the new regime.
// ---------------------------------------------------------------------------

typedef float f32x4_t __attribute__((ext_vector_type(4)));

__device__ __forceinline__ float4 ntload4(const float4* p) {
    f32x4_t v = __builtin_nontemporal_load((const f32x4_t*)p);
    float4 r;
    r.x = v[0]; r.y = v[1]; r.z = v[2]; r.w = v[3];
    return r;
}

__device__ __forceinline__ float wave_sum(float v) {
    for (int off = 32; off; off >>= 1) v += __shfl_xor(v, off);
    return v;
}

// ---------------------------------------------------------------------------
// K1: grid (2 + S/256, B), block 256. Role split on blockIdx.x:
//   bx < 2      : attended[b, bx*256+t] = dot(state[b,:], W[d,:]) + bias[d]
//   bx >= 2     : adj[b, s] = relu(conv1d_same(prev[b,:], cw)[s] + cb0)
// W rows are read-once per launch -> non-temporal.
// ---------------------------------------------------------------------------
__global__ __launch_bounds__(256) void front_kernel(
    const float* __restrict__ state, const float* __restrict__ W,
    const float* __restrict__ bias, const float* __restrict__ prev,
    const float* __restrict__ cw, const float* __restrict__ cb,
    float* __restrict__ attended, float* __restrict__ adj,
    int S, int D, int K) {
    __shared__ __align__(16) float smem[1024];
    int b = blockIdx.y;
    int t = threadIdx.x;

    if (blockIdx.x < 2) {
        // ---- linear part ----
        if (t < D / 4)
            ((float4*)smem)[t] = ((const float4*)(state + (size_t)b * D))[t];
        __syncthreads();
        int d = blockIdx.x * 256 + t;
        const float4* Wrow = (const float4*)(W + (size_t)d * D);
        const float4* sv = (const float4*)smem;
        float acc = bias[d];
#pragma unroll 8
        for (int k = 0; k < 128; ++k) {
            float4 w4 = ntload4(Wrow + k);
            float4 s4 = sv[k];
            acc += w4.x * s4.x + w4.y * s4.y + w4.z * s4.z + w4.w * s4.w;
        }
        attended[(size_t)b * D + d] = acc;
    } else {
        // ---- conv part ----
        int s0 = (blockIdx.x - 2) * 256;
        int pad = K / 2;
        int seglen = 256 + K - 1;
        float* seg = smem;            // seglen floats (<= 256+255)
        float* wk = smem + 512;       // K floats (<= 256)
        for (int i = t; i < seglen; i += 256) {
            int s = s0 - pad + i;
            seg[i] = (s >= 0 && s < S) ? prev[(size_t)b * S + s] : 0.f;
        }
        for (int j = t; j < K; j += 256) wk[j] = cw[j];
        __syncthreads();
        float y = cb[0];
        for (int j = 0; j < K; ++j) y += seg[t + j] * wk[j];
        adj[(size_t)b * S + s0 + t] = fmaxf(y, 0.f);
    }
}

// ---------------------------------------------------------------------------
// K2 (main, single e pass): grid (NCB/4, B), block 256 = 4 waves.
// Each WAVE owns chunk c = bx*4+wave of CH consecutive s for batch b:
//   - recompute ns[b,:] slice in registers from attended (2 KB, L2-hot)
//   - per row: w = dot(ns,e_row)/||e_row||; coef = adj*exp(w)
//              acc += coef*row; z += coef; u[b,s] = coef
// Then the block's 4 waves reduce acc/z through LDS -> ONE partial per block.
// e loads are NON-TEMPORAL (read-once stream, keep L2 for reused data).
// ---------------------------------------------------------------------------
__global__ __launch_bounds__(256) void main_kernel(
    const float* __restrict__ e, const float* __restrict__ attended,
    const float* __restrict__ adj, float* __restrict__ partial,
    float* __restrict__ zbuf, float* __restrict__ u,
    int S, int B, int D, int CH) {
    __shared__ __align__(16) float reds[4 * 512 + 4];   // 4 wave slices + 4 z
    int wave = threadIdx.x >> 6;
    int lane = threadIdx.x & 63;
    int c = blockIdx.x * 4 + wave;
    int b = blockIdx.y;

    // ns slice for this lane (d = lane*4.. and d = 256+lane*4..)
    const float4* att4 = (const float4*)(attended + (size_t)b * D);
    float4 a0 = att4[lane];
    float4 a1 = att4[lane + 64];
    float asq = a0.x * a0.x + a0.y * a0.y + a0.z * a0.z + a0.w * a0.w
              + a1.x * a1.x + a1.y * a1.y + a1.z * a1.z + a1.w * a1.w;
    asq = wave_sum(asq);
    float an = sqrtf(asq);
    if (an == 0.f) an = 1e-10f;
    float ainv = 1.f / an;
    float4 ns0, ns1;
    ns0.x = a0.x * ainv; ns0.y = a0.y * ainv; ns0.z = a0.z * ainv; ns0.w = a0.w * ainv;
    ns1.x = a1.x * ainv; ns1.y = a1.y * ainv; ns1.z = a1.z * ainv; ns1.w = a1.w * ainv;

    int s0 = c * CH;

    // preload the chunk's adj values (uniform per row); shfl per row
    float adjv = 0.f;
    if (CH <= 64 && lane < CH) adjv = adj[(size_t)b * S + s0 + lane];

    float4 acc0 = {0.f, 0.f, 0.f, 0.f};
    float4 acc1 = {0.f, 0.f, 0.f, 0.f};
    float z = 0.f;

    const float4* row4 = (const float4*)(e + ((size_t)s0 * B + b) * D);
    size_t rstride = (size_t)B * D / 4;  // float4 stride between s rows

    float4 x0 = ntload4(row4 + lane);
    float4 x1 = ntload4(row4 + lane + 64);
    for (int i = 0; i < CH; ++i) {
        float4 nx0, nx1;
        if (i + 1 < CH) {
            nx0 = ntload4(row4 + rstride + lane);
            nx1 = ntload4(row4 + rstride + lane + 64);
        }
        float dot = x0.x * ns0.x + x0.y * ns0.y + x0.z * ns0.z + x0.w * ns0.w
                  + x1.x * ns1.x + x1.y * ns1.y + x1.z * ns1.z + x1.w * ns1.w;
        float sq  = x0.x * x0.x + x0.y * x0.y + x0.z * x0.z + x0.w * x0.w
                  + x1.x * x1.x + x1.y * x1.y + x1.z * x1.z + x1.w * x1.w;
        dot = wave_sum(dot);
        sq  = wave_sum(sq);
        float n = sqrtf(sq);
        if (n == 0.f) n = 1e-10f;
        float w = dot / n;
        float av = (CH <= 64) ? __shfl(adjv, i) : adj[(size_t)b * S + s0 + i];
        float coef = av * __expf(w);
        if (lane == 0) u[(size_t)b * S + s0 + i] = coef;
        acc0.x += coef * x0.x; acc0.y += coef * x0.y;
        acc0.z += coef * x0.z; acc0.w += coef * x0.w;
        acc1.x += coef * x1.x; acc1.y += coef * x1.y;
        acc1.z += coef * x1.z; acc1.w += coef * x1.w;
        z += coef;
        x0 = nx0; x1 = nx1;
        row4 += rstride;
    }

    // ---- block-level reduction: 4 wave-chunks -> 1 block partial ----
    float* wsl = reds + (wave << 9);           // 512 floats per wave
    ((float4*)wsl)[lane] = acc0;               // d in [0,256)
    ((float4*)wsl)[lane + 64] = acc1;          // d in [256,512)
    if (lane == 0) reds[2048 + wave] = z;      // coef is wave-uniform: z full
    __syncthreads();
    int t = threadIdx.x;
    if (t < 128) {
        const float4* r4 = (const float4*)reds;
        float4 v0 = r4[t];
        float4 v1 = r4[t + 128];
        float4 v2 = r4[t + 256];
        float4 v3 = r4[t + 384];
        float4 o;
        o.x = v0.x + v1.x + v2.x + v3.x;
        o.y = v0.y + v1.y + v2.y + v3.y;
        o.z = v0.z + v1.z + v2.z + v3.z;
        o.w = v0.w + v1.w + v2.w + v3.w;
        ((float4*)(partial + ((size_t)blockIdx.x * B + b) * D))[t] = o;
    }
    if (t == 0)
        zbuf[(size_t)blockIdx.x * B + b] =
            reds[2048] + reds[2049] + reds[2050] + reds[2051];
}

// ---------------------------------------------------------------------------
// K3: grid (4, B), block 256. Block (q,b):
//   Z = sum_c zbuf[c][b]  (NPART<=64: lanes of wave 0)
//   applied[b, q*128 .. q*128+128) = sum_c partial[c][b][slice] / Z
//   norm_w[b, q*512 .. q*512+512) = u[...] / Z
// partial/u are read-once-then-dead -> non-temporal.
// ---------------------------------------------------------------------------
__global__ __launch_bounds__(256) void combine_kernel(
    const float* __restrict__ partial, const float* __restrict__ zbuf,
    const float* __restrict__ u, float* __restrict__ applied,
    float* __restrict__ norm_w, int S, int B, int D, int NPART) {
    int q = blockIdx.x;       // 0..3
    int b = blockIdx.y;
    int t = threadIdx.x;
    __shared__ __align__(16) float4 red4[8][32];
    __shared__ float zsh;

    // Z reduce (wave 0, lanes < NPART; NPART <= 64)
    float zt = (t < NPART) ? zbuf[(size_t)t * B + b] : 0.f;
    zt = wave_sum(zt);
    if (t == 0) zsh = 1.f / zt;

    // applied quarter: 32 float4 outputs, 8-way chunk split across threads
    int c2 = t >> 5;          // 0..7
    int di = t & 31;          // 0..31
    int d4 = q * 32 + di;     // float4 index into D/4 = 128
    const float4* p4 = (const float4*)partial;
    float4 a = {0.f, 0.f, 0.f, 0.f};
    for (int cix = c2; cix < NPART; cix += 8) {
        float4 x = ntload4(p4 + ((size_t)cix * B + b) * (D >> 2) + d4);
        a.x += x.x; a.y += x.y; a.z += x.z; a.w += x.w;
    }
    red4[c2][di] = a;
    __syncthreads();          // covers zsh too
    float inv = zsh;
    if (t < 32) {
        float4 s = red4[0][t];
#pragma unroll
        for (int j = 1; j < 8; ++j) {
            float4 x = red4[j][t];
            s.x += x.x; s.y += x.y; s.z += x.z; s.w += x.w;
        }
        s.x *= inv; s.y *= inv; s.z *= inv; s.w *= inv;
        ((float4*)(applied + (size_t)b * D))[q * 32 + t] = s;
    }

    // norm_w quarter: 128 float4 per q-slice
    const float4* u4 = (const float4*)(u + (size_t)b * S);
    float4* nw4 = (float4*)(norm_w + (size_t)b * S);
    if (t < 128) {
        int idx = q * (S >> 4) + t;   // S/4 float4 per b, quarter = S/16
        float4 x = ntload4(u4 + idx);
        x.x *= inv; x.y *= inv; x.z *= inv; x.w *= inv;
        nw4[idx] = x;
    }
}

extern "C" void kernel_launch(void* const* d_in, const int* in_sizes, int n_in,
                              void* d_out, int out_size, void* d_ws, size_t ws_size,
                              hipStream_t stream) {
    const float* enc   = (const float*)d_in[0];  // [S,B,D]
    const float* state = (const float*)d_in[1];  // [B,D]
    const float* prev  = (const float*)d_in[2];  // [B,S]
    const float* W     = (const float*)d_in[3];  // [D,D]
    const float* bias  = (const float*)d_in[4];  // [D]
    const float* cw    = (const float*)d_in[5];  // [K]
    const float* cb    = (const float*)d_in[6];  // [1]

    const int S = in_sizes[0] / in_sizes[1];   // 2048
    const int B = in_sizes[2] / S;             // 32
    const int D = in_sizes[1] / B;             // 512
    const int K = in_sizes[5];                 // 147

    float* out     = (float*)d_out;
    float* applied = out;                    // B*D
    float* norm_w  = out + (size_t)B * D;    // B*S

    const int NCHUNK = 256;       // wave-chunks per batch row (8 waves/SIMD)
    const int CH = S / NCHUNK;    // 8 s-rows per wave-chunk
    const int NPART = NCHUNK / 4; // 64 block partials per batch row

    float* ws       = (float*)d_ws;
    float* attended = ws;                            // B*D
    float* adj      = attended + (size_t)B * D;      // B*S
    float* u        = adj + (size_t)B * S;           // B*S
    float* zbuf     = u + (size_t)B * S;             // NPART*B
    float* partial  = zbuf + (size_t)NPART * B;      // NPART*B*D

    front_kernel<<<dim3(2 + S / 256, B), 256, 0, stream>>>(
        state, W, bias, prev, cw, cb, attended, adj, S, D, K);
    main_kernel<<<dim3(NPART, B), 256, 0, stream>>>(
        enc, attended, adj, partial, zbuf, u, S, B, D, CH);
    combine_kernel<<<dim3(4, B), 256, 0, stream>>>(
        partial, zbuf, u, applied, norm_w, S, B, D, NPART);
}

// Round 9
// 208.633 us; speedup vs baseline: 1.0699x; 1.0699x over previous
//
#include <hip/hip_runtime.h>
#include <math.h>

// ---------------------------------------------------------------------------
// TimeAttender: S=2048, B=32, D=512, K=147
// out = concat(applied [B*D], norm_w [B*S])
//
// Math notes:
//  * prev_probs normalizer and softmax Z cancel in
//      norm_w = adj * exp(w) / sum_s(adj * exp(w))
//  * w is a cosine similarity in [-1,1] -> exp(w) in [0.37, 2.72]:
//    no max-subtraction needed; apply pass is single-pass over e.
//  * SESSION LEDGER (R0..R8) — read before "optimizing":
//    - Fixed harness cost ~157 us (512 MiB poison fills + resets) dominates.
//    - R2: last-block fusion w/ __threadfence = L2-writeback storm (+55).
//    - R4: contiguous-vs-strided e walk: NEUTRAL. Pattern not the limiter.
//    - R5: register-resident 16-row pipeline: VGPR spills (+56).
//    - R6: global_load_lds ring + counted vmcnt: +29 (compiler drains
//      vmcnt before aliasing ds_reads; guide §5 m131-m141 trap).
//    - R7: NON-TEMPORAL loads on the e stream: -9.1 us (210.9, BEST).
//      nt avoids L2 allocation for the 134 MB read-once stream -> live set
//      (partial/u/adj/attended) stays resident.
//    - R8: nt on W/partial/u + NCHUNK 256: +12.3 REGRESSION. partial/u are
//      producer->consumer intermediates (L2-warm), nt punishes the hit
//      path; bigger NCHUNK doubles partial traffic for zero main gain.
//      nt is ONLY for truly-cold read-once streams.
//    - This round: exact revert to the R7 winner. All catalog mechanisms
//      tested; remaining time = ~157 us harness + ~54 us kernels with the
//      e-read at ~4 TB/s effective across 5 independent structures.
// ---------------------------------------------------------------------------

typedef float f32x4_t __attribute__((ext_vector_type(4)));

__device__ __forceinline__ float4 ntload4(const float4* p) {
    f32x4_t v = __builtin_nontemporal_load((const f32x4_t*)p);
    float4 r;
    r.x = v[0]; r.y = v[1]; r.z = v[2]; r.w = v[3];
    return r;
}

__device__ __forceinline__ float wave_sum(float v) {
    for (int off = 32; off; off >>= 1) v += __shfl_xor(v, off);
    return v;
}

// ---------------------------------------------------------------------------
// K1: grid (2 + S/256, B), block 256. Role split on blockIdx.x:
//   bx < 2      : attended[b, bx*256+t] = dot(state[b,:], W[d,:]) + bias[d]
//   bx >= 2     : adj[b, s] = relu(conv1d_same(prev[b,:], cw)[s] + cb0)
// ---------------------------------------------------------------------------
__global__ __launch_bounds__(256) void front_kernel(
    const float* __restrict__ state, const float* __restrict__ W,
    const float* __restrict__ bias, const float* __restrict__ prev,
    const float* __restrict__ cw, const float* __restrict__ cb,
    float* __restrict__ attended, float* __restrict__ adj,
    int S, int D, int K) {
    __shared__ __align__(16) float smem[1024];
    int b = blockIdx.y;
    int t = threadIdx.x;

    if (blockIdx.x < 2) {
        // ---- linear part ----
        if (t < D / 4)
            ((float4*)smem)[t] = ((const float4*)(state + (size_t)b * D))[t];
        __syncthreads();
        int d = blockIdx.x * 256 + t;
        const float4* Wrow = (const float4*)(W + (size_t)d * D);
        const float4* sv = (const float4*)smem;
        float acc = bias[d];
#pragma unroll 8
        for (int k = 0; k < 128; ++k) {
            float4 w4 = Wrow[k];
            float4 s4 = sv[k];
            acc += w4.x * s4.x + w4.y * s4.y + w4.z * s4.z + w4.w * s4.w;
        }
        attended[(size_t)b * D + d] = acc;
    } else {
        // ---- conv part ----
        int s0 = (blockIdx.x - 2) * 256;
        int pad = K / 2;
        int seglen = 256 + K - 1;
        float* seg = smem;            // seglen floats (<= 256+255)
        float* wk = smem + 512;       // K floats (<= 256)
        for (int i = t; i < seglen; i += 256) {
            int s = s0 - pad + i;
            seg[i] = (s >= 0 && s < S) ? prev[(size_t)b * S + s] : 0.f;
        }
        for (int j = t; j < K; j += 256) wk[j] = cw[j];
        __syncthreads();
        float y = cb[0];
        for (int j = 0; j < K; ++j) y += seg[t + j] * wk[j];
        adj[(size_t)b * S + s0 + t] = fmaxf(y, 0.f);
    }
}

// ---------------------------------------------------------------------------
// K2 (main, single e pass): grid (NCB/4, B), block 256 = 4 waves.
// Each WAVE owns chunk c = bx*4+wave of CH consecutive s for batch b:
//   - recompute ns[b,:] slice in registers from attended (2 KB, L2-hot)
//   - per row: w = dot(ns,e_row)/||e_row||; coef = adj*exp(w)
//              acc += coef*row; z += coef; u[b,s] = coef
// Then the block's 4 waves reduce acc/z through LDS -> ONE partial per block.
// e loads are NON-TEMPORAL (read-once stream, keep L2 for reused data).
// ---------------------------------------------------------------------------
__global__ __launch_bounds__(256) void main_kernel(
    const float* __restrict__ e, const float* __restrict__ attended,
    const float* __restrict__ adj, float* __restrict__ partial,
    float* __restrict__ zbuf, float* __restrict__ u,
    int S, int B, int D, int CH) {
    __shared__ __align__(16) float reds[4 * 512 + 4];   // 4 wave slices + 4 z
    int wave = threadIdx.x >> 6;
    int lane = threadIdx.x & 63;
    int c = blockIdx.x * 4 + wave;
    int b = blockIdx.y;

    // ns slice for this lane (d = lane*4.. and d = 256+lane*4..)
    const float4* att4 = (const float4*)(attended + (size_t)b * D);
    float4 a0 = att4[lane];
    float4 a1 = att4[lane + 64];
    float asq = a0.x * a0.x + a0.y * a0.y + a0.z * a0.z + a0.w * a0.w
              + a1.x * a1.x + a1.y * a1.y + a1.z * a1.z + a1.w * a1.w;
    asq = wave_sum(asq);
    float an = sqrtf(asq);
    if (an == 0.f) an = 1e-10f;
    float ainv = 1.f / an;
    float4 ns0, ns1;
    ns0.x = a0.x * ainv; ns0.y = a0.y * ainv; ns0.z = a0.z * ainv; ns0.w = a0.w * ainv;
    ns1.x = a1.x * ainv; ns1.y = a1.y * ainv; ns1.z = a1.z * ainv; ns1.w = a1.w * ainv;

    int s0 = c * CH;

    // preload the chunk's adj values (uniform per row); shfl per row
    float adjv = 0.f;
    if (CH <= 64 && lane < CH) adjv = adj[(size_t)b * S + s0 + lane];

    float4 acc0 = {0.f, 0.f, 0.f, 0.f};
    float4 acc1 = {0.f, 0.f, 0.f, 0.f};
    float z = 0.f;

    const float4* row4 = (const float4*)(e + ((size_t)s0 * B + b) * D);
    size_t rstride = (size_t)B * D / 4;  // float4 stride between s rows

    float4 x0 = ntload4(row4 + lane);
    float4 x1 = ntload4(row4 + lane + 64);
    for (int i = 0; i < CH; ++i) {
        float4 nx0, nx1;
        if (i + 1 < CH) {
            nx0 = ntload4(row4 + rstride + lane);
            nx1 = ntload4(row4 + rstride + lane + 64);
        }
        float dot = x0.x * ns0.x + x0.y * ns0.y + x0.z * ns0.z + x0.w * ns0.w
                  + x1.x * ns1.x + x1.y * ns1.y + x1.z * ns1.z + x1.w * ns1.w;
        float sq  = x0.x * x0.x + x0.y * x0.y + x0.z * x0.z + x0.w * x0.w
                  + x1.x * x1.x + x1.y * x1.y + x1.z * x1.z + x1.w * x1.w;
        dot = wave_sum(dot);
        sq  = wave_sum(sq);
        float n = sqrtf(sq);
        if (n == 0.f) n = 1e-10f;
        float w = dot / n;
        float av = (CH <= 64) ? __shfl(adjv, i) : adj[(size_t)b * S + s0 + i];
        float coef = av * __expf(w);
        if (lane == 0) u[(size_t)b * S + s0 + i] = coef;
        acc0.x += coef * x0.x; acc0.y += coef * x0.y;
        acc0.z += coef * x0.z; acc0.w += coef * x0.w;
        acc1.x += coef * x1.x; acc1.y += coef * x1.y;
        acc1.z += coef * x1.z; acc1.w += coef * x1.w;
        z += coef;
        x0 = nx0; x1 = nx1;
        row4 += rstride;
    }

    // ---- block-level reduction: 4 wave-chunks -> 1 block partial ----
    float* wsl = reds + (wave << 9);           // 512 floats per wave
    ((float4*)wsl)[lane] = acc0;               // d in [0,256)
    ((float4*)wsl)[lane + 64] = acc1;          // d in [256,512)
    if (lane == 0) reds[2048 + wave] = z;      // coef is wave-uniform: z full
    __syncthreads();
    int t = threadIdx.x;
    if (t < 128) {
        const float4* r4 = (const float4*)reds;
        float4 v0 = r4[t];
        float4 v1 = r4[t + 128];
        float4 v2 = r4[t + 256];
        float4 v3 = r4[t + 384];
        float4 o;
        o.x = v0.x + v1.x + v2.x + v3.x;
        o.y = v0.y + v1.y + v2.y + v3.y;
        o.z = v0.z + v1.z + v2.z + v3.z;
        o.w = v0.w + v1.w + v2.w + v3.w;
        ((float4*)(partial + ((size_t)blockIdx.x * B + b) * D))[t] = o;
    }
    if (t == 0)
        zbuf[(size_t)blockIdx.x * B + b] =
            reds[2048] + reds[2049] + reds[2050] + reds[2051];
}

// ---------------------------------------------------------------------------
// K3: grid (4, B), block 256. Block (q,b):
//   Z = sum_c zbuf[c][b]  (NPART<=64: lanes of wave 0)
//   applied[b, q*128 .. q*128+128) = sum_c partial[c][b][slice] / Z
//   norm_w[b, q*512 .. q*512+512) = u[...] / Z
// ---------------------------------------------------------------------------
__global__ __launch_bounds__(256) void combine_kernel(
    const float* __restrict__ partial, const float* __restrict__ zbuf,
    const float* __restrict__ u, float* __restrict__ applied,
    float* __restrict__ norm_w, int S, int B, int D, int NPART) {
    int q = blockIdx.x;       // 0..3
    int b = blockIdx.y;
    int t = threadIdx.x;
    __shared__ __align__(16) float4 red4[8][32];
    __shared__ float zsh;

    // Z reduce (wave 0, lanes < NPART)
    float zt = (t < NPART) ? zbuf[(size_t)t * B + b] : 0.f;
    zt = wave_sum(zt);
    if (t == 0) zsh = 1.f / zt;

    // applied quarter: 32 float4 outputs, 8-way chunk split across threads
    int c2 = t >> 5;          // 0..7
    int di = t & 31;          // 0..31
    int d4 = q * 32 + di;     // float4 index into D/4 = 128
    const float4* p4 = (const float4*)partial;
    float4 a = {0.f, 0.f, 0.f, 0.f};
    for (int cix = c2; cix < NPART; cix += 8) {
        float4 x = p4[((size_t)cix * B + b) * (D >> 2) + d4];
        a.x += x.x; a.y += x.y; a.z += x.z; a.w += x.w;
    }
    red4[c2][di] = a;
    __syncthreads();          // covers zsh too
    float inv = zsh;
    if (t < 32) {
        float4 s = red4[0][t];
#pragma unroll
        for (int j = 1; j < 8; ++j) {
            float4 x = red4[j][t];
            s.x += x.x; s.y += x.y; s.z += x.z; s.w += x.w;
        }
        s.x *= inv; s.y *= inv; s.z *= inv; s.w *= inv;
        ((float4*)(applied + (size_t)b * D))[q * 32 + t] = s;
    }

    // norm_w quarter: 128 float4 per q-slice
    const float4* u4 = (const float4*)(u + (size_t)b * S);
    float4* nw4 = (float4*)(norm_w + (size_t)b * S);
    if (t < 128) {
        int idx = q * (S >> 4) + t;   // S/4 float4 per b, quarter = S/16
        float4 x = u4[idx];
        x.x *= inv; x.y *= inv; x.z *= inv; x.w *= inv;
        nw4[idx] = x;
    }
}

extern "C" void kernel_launch(void* const* d_in, const int* in_sizes, int n_in,
                              void* d_out, int out_size, void* d_ws, size_t ws_size,
                              hipStream_t stream) {
    const float* enc   = (const float*)d_in[0];  // [S,B,D]
    const float* state = (const float*)d_in[1];  // [B,D]
    const float* prev  = (const float*)d_in[2];  // [B,S]
    const float* W     = (const float*)d_in[3];  // [D,D]
    const float* bias  = (const float*)d_in[4];  // [D]
    const float* cw    = (const float*)d_in[5];  // [K]
    const float* cb    = (const float*)d_in[6];  // [1]

    const int S = in_sizes[0] / in_sizes[1];   // 2048
    const int B = in_sizes[2] / S;             // 32
    const int D = in_sizes[1] / B;             // 512
    const int K = in_sizes[5];                 // 147

    float* out     = (float*)d_out;
    float* applied = out;                    // B*D
    float* norm_w  = out + (size_t)B * D;    // B*S

    const int NCHUNK = 128;       // wave-chunks per batch row
    const int CH = S / NCHUNK;    // 16 s-rows per wave-chunk
    const int NPART = NCHUNK / 4; // 32 block partials per batch row

    float* ws       = (float*)d_ws;
    float* attended = ws;                            // B*D
    float* adj      = attended + (size_t)B * D;      // B*S
    float* u        = adj + (size_t)B * S;           // B*S
    float* zbuf     = u + (size_t)B * S;             // NPART*B
    float* partial  = zbuf + (size_t)NPART * B;      // NPART*B*D

    front_kernel<<<dim3(2 + S / 256, B), 256, 0, stream>>>(
        state, W, bias, prev, cw, cb, attended, adj, S, D, K);
    main_kernel<<<dim3(NPART, B), 256, 0, stream>>>(
        enc, attended, adj, partial, zbuf, u, S, B, D, CH);
    combine_kernel<<<dim3(4, B), 256, 0, stream>>>(
        partial, zbuf, u, applied, norm_w, S, B, D, NPART);
}